// Round 9
// baseline (10942.154 us; speedup 1.0000x reference)
//
#include <hip/hip_runtime.h>
#include <hip/hip_bf16.h>

typedef __bf16 bf16x8 __attribute__((ext_vector_type(8)));
typedef float  f32x4  __attribute__((ext_vector_type(4)));
typedef float  f32x2  __attribute__((ext_vector_type(2)));  // clang vec for NT builtins
typedef unsigned short u16;
typedef unsigned int   u32;

#define SEQ   512
#define BATCH 64
#define INP   1024
#define HID   1024
#define NREC  64     // recurrence blocks
#define NGRID 256    // total blocks (64 recurrence + 192 heater)

// ---- workspace layout (bytes) ----
#define WC_OFF    0ull
#define HSEQ_OFF  (WC_OFF + 16777216ull)
#define BIAS_OFF  (HSEQ_OFF + 67239936ull)
#define FLAGS_OFF (BIAS_OFF + 16384ull)
#define XTRA_OFF  (FLAGS_OFF + 16384ull)
#define WS_NEED_XC (XTRA_OFF + 67108864ull)
#define WS_NEED_XG (XTRA_OFF + 536870912ull)

// ---- probe area: inside the xg region (overwritten by lstm_xg afterwards) --
// R8 verdict: modes 0-2 (barrier / busy-spin / +store-drain) all ~free
// (3x1024 iters cost <=~50us total). R9 probes decompose the POST-barrier
// step body: A = rec-identical h[t]-pattern reads (shared fresh 128KB/iter),
// B = rec-identical W_hh-pattern reads (own static 128KB from real wc).
#define N_PROBE_IT 256
#define PROBE_SPIN_BOUND (1 << 14)
#define PROBE_BASE (XTRA_OFF + 402653184ull)    // xg + 384 MB
#define AREG_OFF   (PROBE_BASE + (2ull << 20))  // 32 MB A-read region

__device__ __forceinline__ u16 f2bf(float f) {
    u32 u = __float_as_uint(f);
    u = (u + 0x7FFFu + ((u >> 16) & 1u)) >> 16;
    return (u16)u;
}

__device__ __forceinline__ bf16x8 ld8(const u16* p) {
    return *reinterpret_cast<const bf16x8*>(p);
}

__device__ __forceinline__ bf16x8 cvt8(const float* p) {
    float4 lo = *reinterpret_cast<const float4*>(p);
    float4 hi = *reinterpret_cast<const float4*>(p + 4);
    union { __hip_bfloat162 h2[4]; bf16x8 v; } u;
    u.h2[0] = __float22bfloat162_rn(float2{lo.x, lo.y});
    u.h2[1] = __float22bfloat162_rn(float2{lo.z, lo.w});
    u.h2[2] = __float22bfloat162_rn(float2{hi.x, hi.y});
    u.h2[3] = __float22bfloat162_rn(float2{hi.z, hi.w});
    return u.v;
}

__device__ __forceinline__ float sigmoidf_fast(float x) {
    return 1.0f / (1.0f + __expf(-x));
}
__device__ __forceinline__ float tanhf_fast(float x) {
    return 2.0f / (1.0f + __expf(-2.0f * x)) - 1.0f;
}

// ---------------- prep ----------------
__global__ void lstm_prep(const float* __restrict__ wih,
                          const float* __restrict__ whh,
                          const float* __restrict__ bih,
                          const float* __restrict__ bhh,
                          const float* __restrict__ xf,
                          u16* __restrict__ wc, u16* __restrict__ hseq,
                          float* __restrict__ bias, u32* __restrict__ flags,
                          u16* __restrict__ xc, int do_x) {
    const long long NW = 8388608ll;
    const long long NB = 4096ll;
    const long long NH = 65536ll;
    const long long NF = 2080ll;
    const long long NX = do_x ? 33554432ll : 0ll;
    const long long total = NW + NB + NH + NF + NX;
    long long stride = (long long)gridDim.x * blockDim.x;
    for (long long i = (long long)blockIdx.x * blockDim.x + threadIdx.x;
         i < total; i += stride) {
        if (i < NW) {
            long long row = i >> 11;
            long long col = i & 2047;
            float v = (col < 1024) ? wih[row * 1024 + col]
                                   : whh[row * 1024 + (col - 1024)];
            wc[i] = f2bf(v);
        } else if (i < NW + NB) {
            long long j = i - NW;
            bias[j] = bih[j] + bhh[j];
        } else if (i < NW + NB + NH) {
            hseq[i - NW - NB] = 0;
        } else if (i < NW + NB + NH + NF) {
            flags[i - NW - NB - NH] = 0;
        } else {
            long long j = i - NW - NB - NH - NF;
            xc[j] = f2bf(xf[j]);
        }
    }
}

// ---------------- probe init: zero 4 flag regions; agent-store-fill the
//                  A-region so its lines sit at the coherent point (MALL),
//                  replicating rec's freshly-written h[t] lines ------------
__global__ void probe_init(u32* __restrict__ pf, u32* __restrict__ areg32) {
    long long idx = (long long)blockIdx.x * blockDim.x + threadIdx.x;
    long long stride = (long long)gridDim.x * blockDim.x;
    for (long long i = idx; i < 16384; i += stride) pf[i] = 0;
    for (long long i = idx; i < 8388608; i += stride)   // 32 MB
        __hip_atomic_store(areg32 + i, 0x3f803f80u,
                           __ATOMIC_RELAXED, __HIP_MEMORY_SCOPE_AGENT);
}

// ---------------- step-body probes ----------------
// mode 0: barrier only (R8 baseline, re-run for same-round comparison)
// mode 3: barrier + A-reads  (all blocks read same fresh 128KB slice/iter)
// mode 4: barrier + B-reads  (own static 128KB W_hh slice from real wc)
// mode 5: barrier + A + B    (interaction / eviction)
__global__ __launch_bounds__(256, 1) void lstm_probe(
    u32* __restrict__ pflags, const u16* __restrict__ wc,
    const u16* __restrict__ areg, int mode) {

    __shared__ float part[16384];   // 64 KB, pins 1 block/CU like rec
    const int tid = threadIdx.x;

    if (blockIdx.x >= NREC) {
        // heater (rec-identical shape, bounded)
        volatile int* mb = (volatile int*)&part[0];
        if (tid == 0) *mb = 0;
        __syncthreads();
        union { u32 u[4]; bf16x8 v; } ja, jb;
        #pragma unroll
        for (int i = 0; i < 4; ++i) {
            ja.u[i] = (u32)tid * 2654435761u + i;
            jb.u[i] = (u32)tid * 40503u + 7u * i + 1u;
        }
        f32x4 hacc[8];
        #pragma unroll
        for (int j = 0; j < 8; ++j) hacc[j] = (f32x4){0.f, 0.f, 0.f, 0.f};
        const u32* done = pflags + 2048;
        for (int chunk = 0; chunk < 4096; ++chunk) {
            #pragma unroll 1
            for (int it = 0; it < 256; ++it) {
                #pragma unroll
                for (int j = 0; j < 8; ++j)
                    hacc[j] = __builtin_amdgcn_mfma_f32_16x16x32_bf16(
                        ja.v, jb.v, hacc[j], 0, 0, 0);
            }
            if (tid < 64) {
                u32 d = __hip_atomic_load(done, __ATOMIC_RELAXED,
                                          __HIP_MEMORY_SCOPE_AGENT);
                if (d) *mb = 1;
            }
            if (*mb) break;
        }
        float s = 0.f;
        #pragma unroll
        for (int j = 0; j < 8; ++j)
            s += hacc[j][0] + hacc[j][1] + hacc[j][2] + hacc[j][3];
        asm volatile("" :: "v"(s));
        return;
    }

    const int w    = tid >> 6;
    const int lane = tid & 63;
    const int quad = lane >> 4;
    const int l16  = lane & 15;
    const int cu   = blockIdx.x;
    const int col0 = cu * 16;

    const u16* wb = wc + (size_t)(col0 + l16) * 2048 + (size_t)w * 256
                       + (size_t)quad * 8 + 1024;

    u32 accb0 = 0, accb1 = 0, accb2 = 0, accb3 = 0;

    #pragma unroll 1
    for (int t = 0; t < N_PROBE_IT; ++t) {
        if (t > 0) {
            const u32* fl = pflags + ((u32)lane << 5);
            #pragma unroll 1
            for (int sp = 0; sp < PROBE_SPIN_BOUND; ++sp) {
                u32 f = __hip_atomic_load(fl, __ATOMIC_RELAXED,
                                          __HIP_MEMORY_SCOPE_AGENT);
                if (__ballot((int)f >= t) == 0xFFFFFFFFFFFFFFFFull) break;
                __builtin_amdgcn_s_sleep(1);
            }
            asm volatile("" ::: "memory");
        }
        if (mode == 3 || mode == 5) {
            const u16* As = areg + (size_t)t * 65536 + (size_t)l16 * 1024
                          + (size_t)w * 256 + (size_t)quad * 8;
            #pragma unroll 4
            for (int kk = 0; kk < 8; ++kk)
                #pragma unroll
                for (int mt = 0; mt < 4; ++mt) {
                    union { bf16x8 v; u32 u[4]; } uu;
                    uu.v = ld8(As + (size_t)mt * 16 * 1024 + kk * 32);
                    accb0 ^= uu.u[0]; accb1 ^= uu.u[1];
                    accb2 ^= uu.u[2]; accb3 ^= uu.u[3];
                }
        }
        if (mode == 4 || mode == 5) {
            #pragma unroll 4
            for (int kk = 0; kk < 8; ++kk)
                #pragma unroll
                for (int g = 0; g < 4; ++g) {
                    union { bf16x8 v; u32 u[4]; } uu;
                    uu.v = ld8(wb + (size_t)g * 1024 * 2048 + kk * 32);
                    accb0 ^= uu.u[0]; accb1 ^= uu.u[1];
                    accb2 ^= uu.u[2]; accb3 ^= uu.u[3];
                }
        }
        __syncthreads();
        if (tid == 0) {
            __hip_atomic_store(pflags + ((u32)cu << 5), (u32)(t + 1),
                               __ATOMIC_RELAXED, __HIP_MEMORY_SCOPE_AGENT);
        }
    }
    asm volatile("" :: "v"(accb0), "v"(accb1), "v"(accb2), "v"(accb3));
    if (cu == 0 && tid == 0)
        __hip_atomic_store(pflags + 2048, 1u,
                           __ATOMIC_RELAXED, __HIP_MEMORY_SCOPE_AGENT);
}

// ---------------- phase 1: XG[t] = x[t] @ W_ih^T, fully parallel ----------
__global__ __launch_bounds__(256, 1) void lstm_xg(
    const float* __restrict__ x, const u16* __restrict__ wc,
    float* __restrict__ xg) {
    const int tid  = threadIdx.x;
    const int w    = tid >> 6;
    const int lane = tid & 63;
    const int quad = lane >> 4;
    const int l16  = lane & 15;
    const int job  = blockIdx.x * 4 + w;
    const int cu   = job & 63;
    const int t    = job >> 6;
    const int col0 = cu * 16;

    const float* Abase = x + (size_t)t * 65536 + (size_t)l16 * 1024 + quad * 8;
    const u16*   Bbase = wc + (size_t)(col0 + l16) * 2048 + quad * 8;

    f32x4 acc[4][4];
    #pragma unroll
    for (int g = 0; g < 4; ++g)
        #pragma unroll
        for (int mt = 0; mt < 4; ++mt)
            acc[g][mt] = (f32x4){0.f, 0.f, 0.f, 0.f};

    #pragma unroll 4
    for (int kk = 0; kk < 32; ++kk) {
        bf16x8 afr[4], bfr[4];
        #pragma unroll
        for (int mt = 0; mt < 4; ++mt)
            afr[mt] = cvt8(Abase + (size_t)mt * 16 * 1024 + kk * 32);
        #pragma unroll
        for (int g = 0; g < 4; ++g)
            bfr[g] = ld8(Bbase + (size_t)g * 1024 * 2048 + kk * 32);
        #pragma unroll
        for (int g = 0; g < 4; ++g)
            #pragma unroll
            for (int mt = 0; mt < 4; ++mt)
                acc[g][mt] = __builtin_amdgcn_mfma_f32_16x16x32_bf16(
                    afr[mt], bfr[g], acc[g][mt], 0, 0, 0);
    }

    float* Obase = xg + (size_t)t * 262144 + (size_t)(quad * 4) * 4096
                      + col0 + l16;
    #pragma unroll
    for (int g = 0; g < 4; ++g)
        #pragma unroll
        for (int mt = 0; mt < 4; ++mt)
            #pragma unroll
            for (int r = 0; r < 4; ++r)
                Obase[(size_t)(mt * 16 + r) * 4096 + g * 1024] = acc[g][mt][r];
}

// ---------------- persistent recurrence + DVFS heater ----------------
// R9 rec deltas (xg mode): (a) the 32 W_hh B-fragment loads are PRE-ISSUED
//   before the barrier poll — the poll's vmcnt(0) drains them under the wait,
//   so the h-part starts with B in registers; (b) xg/km loads moved AFTER the
//   barrier — their HBM drain leaves the pre-poll serial path and completes
//   under the h-part MFMAs. R8 probes: barrier/publish/drain all ~free.
__global__ __launch_bounds__(256, 1) void lstm_rec(
    const float* __restrict__ x, const u16* __restrict__ xc,
    const u16* __restrict__ wc,
    const float* __restrict__ bias, const float* __restrict__ km,
    u16* __restrict__ hseq, float* __restrict__ out,
    u32* __restrict__ flags, const int* __restrict__ trainp,
    const float* __restrict__ xg) {

    __shared__ float part[4][4][BATCH][16];

    const int tid = threadIdx.x;

    if (blockIdx.x >= NREC) {
        volatile int* mb = (volatile int*)&part[0][0][0][0];
        if (tid == 0) *mb = 0;
        __syncthreads();
        union { u32 u[4]; bf16x8 v; } ja, jb;
        #pragma unroll
        for (int i = 0; i < 4; ++i) {
            ja.u[i] = (u32)tid * 2654435761u + i;
            jb.u[i] = (u32)tid * 40503u + 7u * i + 1u;
        }
        f32x4 hacc[8];
        #pragma unroll
        for (int j = 0; j < 8; ++j) hacc[j] = (f32x4){0.f, 0.f, 0.f, 0.f};
        const u32* done = flags + 2048;
        for (int chunk = 0; chunk < 4096; ++chunk) {
            #pragma unroll 1
            for (int it = 0; it < 256; ++it) {
                #pragma unroll
                for (int j = 0; j < 8; ++j)
                    hacc[j] = __builtin_amdgcn_mfma_f32_16x16x32_bf16(
                        ja.v, jb.v, hacc[j], 0, 0, 0);
            }
            if (tid < 64) {
                u32 d = __hip_atomic_load(done, __ATOMIC_RELAXED,
                                          __HIP_MEMORY_SCOPE_AGENT);
                if (d) *mb = 1;
            }
            if (*mb) break;
        }
        float s = 0.f;
        #pragma unroll
        for (int j = 0; j < 8; ++j)
            s += hacc[j][0] + hacc[j][1] + hacc[j][2] + hacc[j][3];
        asm volatile("" :: "v"(s));
        return;
    }

    const int w    = tid >> 6;
    const int lane = tid & 63;
    const int quad = lane >> 4;
    const int l16  = lane & 15;
    const int cu   = blockIdx.x;
    const int col0 = cu * 16;

    const int training = trainp[0];
    const float scale = training ? (1.0f / 0.9f) : 1.0f;

    const u16* wbase = wc + (size_t)(col0 + l16) * 2048 + (size_t)w * 256
                          + (size_t)quad * 8;

    const int cj2 = (tid & 7) * 2;
    const int cb0 = tid >> 3;
    float bi[4][2];
    #pragma unroll
    for (int g = 0; g < 4; ++g) {
        bi[g][0] = bias[g * 1024 + col0 + cj2];
        bi[g][1] = bias[g * 1024 + col0 + cj2 + 1];
    }

    float creg[2][2] = {{0.f, 0.f}, {0.f, 0.f}};

    #pragma unroll 1
    for (int t = 0; t < SEQ; ++t) {
        // ---- (a) pre-issue W_hh B-fragments: drained by the poll's vmcnt ----
        bf16x8 whr[8][4];
        #pragma unroll
        for (int kk = 0; kk < 8; ++kk)
            #pragma unroll
            for (int g = 0; g < 4; ++g)
                whr[kk][g] = ld8(wbase + 1024
                                 + (size_t)g * 1024 * 2048 + kk * 32);

        f32x4 acc[4][4];
        #pragma unroll
        for (int g = 0; g < 4; ++g)
            #pragma unroll
            for (int mt = 0; mt < 4; ++mt)
                acc[g][mt] = (f32x4){0.f, 0.f, 0.f, 0.f};

        // fallback modes (never active in xg runs): x-part before barrier
        if (xg == nullptr && xc != nullptr) {
            const u16* Arow = xc + (size_t)t * 65536
                                 + (size_t)l16 * 1024 + (size_t)w * 256
                                 + (size_t)quad * 8;
            #pragma unroll 4
            for (int kk = 0; kk < 8; ++kk) {
                bf16x8 afr[4], bfr[4];
                #pragma unroll
                for (int mt = 0; mt < 4; ++mt)
                    afr[mt] = ld8(Arow + (size_t)mt * 16 * 1024 + kk * 32);
                #pragma unroll
                for (int g = 0; g < 4; ++g)
                    bfr[g] = ld8(wbase + (size_t)g * 1024 * 2048 + kk * 32);
                #pragma unroll
                for (int g = 0; g < 4; ++g)
                    #pragma unroll
                    for (int mt = 0; mt < 4; ++mt)
                        acc[g][mt] = __builtin_amdgcn_mfma_f32_16x16x32_bf16(
                            afr[mt], bfr[g], acc[g][mt], 0, 0, 0);
            }
        } else if (xg == nullptr) {
            const float* Arow = x + (size_t)t * (BATCH * INP)
                                  + (size_t)l16 * 1024 + (size_t)w * 256
                                  + (size_t)quad * 8;
            #pragma unroll 4
            for (int kk = 0; kk < 8; ++kk) {
                bf16x8 afr[4], bfr[4];
                #pragma unroll
                for (int mt = 0; mt < 4; ++mt)
                    afr[mt] = cvt8(Arow + (size_t)mt * 16 * 1024 + kk * 32);
                #pragma unroll
                for (int g = 0; g < 4; ++g)
                    bfr[g] = ld8(wbase + (size_t)g * 1024 * 2048 + kk * 32);
                #pragma unroll
                for (int g = 0; g < 4; ++g)
                    #pragma unroll
                    for (int mt = 0; mt < 4; ++mt)
                        acc[g][mt] = __builtin_amdgcn_mfma_f32_16x16x32_bf16(
                            afr[mt], bfr[g], acc[g][mt], 0, 0, 0);
            }
        }

        // ---- distributed barrier ----
        if (t > 0) {
            const u32* fl = flags + ((u32)lane << 5);
            while (true) {
                u32 f = __hip_atomic_load(fl, __ATOMIC_RELAXED,
                                          __HIP_MEMORY_SCOPE_AGENT);
                if (__ballot((int)f >= t) == 0xFFFFFFFFFFFFFFFFull) break;
                __builtin_amdgcn_s_sleep(1);
            }
            asm volatile("" ::: "memory");
        }

        // ---- (b) xg/km loads post-barrier: complete under h-part MFMAs ----
        f32x2 kmv[2];
        kmv[0] = __builtin_nontemporal_load(reinterpret_cast<const f32x2*>(
            &km[(size_t)t * 65536 + (size_t)cb0 * 1024 + col0 + cj2]));
        kmv[1] = __builtin_nontemporal_load(reinterpret_cast<const f32x2*>(
            &km[(size_t)t * 65536 + (size_t)(cb0 + 32) * 1024 + col0 + cj2]));
        float xgv[4][2][2];
        if (xg != nullptr) {
            const float* xgp = xg + (size_t)t * 262144;
            #pragma unroll
            for (int r = 0; r < 2; ++r) {
                int b = cb0 + 32 * r;
                #pragma unroll
                for (int g = 0; g < 4; ++g) {
                    f32x2 v = __builtin_nontemporal_load(
                        reinterpret_cast<const f32x2*>(
                            &xgp[(size_t)b * 4096 + g * 1024 + col0 + cj2]));
                    xgv[g][r][0] = v[0];
                    xgv[g][r][1] = v[1];
                }
            }
        }

        // ---- h-part (B already in registers) ----
        {
            const u16* Hrow = hseq + (size_t)t * 65536
                                   + (size_t)l16 * 1024 + (size_t)w * 256
                                   + (size_t)quad * 8;
            #pragma unroll 4
            for (int kk = 0; kk < 8; ++kk) {
                bf16x8 afr[4];
                #pragma unroll
                for (int mt = 0; mt < 4; ++mt)
                    afr[mt] = ld8(Hrow + (size_t)mt * 16 * 1024 + kk * 32);
                #pragma unroll
                for (int g = 0; g < 4; ++g)
                    #pragma unroll
                    for (int mt = 0; mt < 4; ++mt)
                        acc[g][mt] = __builtin_amdgcn_mfma_f32_16x16x32_bf16(
                            afr[mt], whr[kk][g], acc[g][mt], 0, 0, 0);
            }
        }

        #pragma unroll
        for (int g = 0; g < 4; ++g)
            #pragma unroll
            for (int mt = 0; mt < 4; ++mt)
                #pragma unroll
                for (int r = 0; r < 4; ++r)
                    part[w][g][mt * 16 + quad * 4 + r][l16] = acc[g][mt][r];

        __syncthreads();

        u16* hout = hseq + (size_t)(t + 1) * 65536;
        const int have_xg = (xg != nullptr);
        #pragma unroll
        for (int r = 0; r < 2; ++r) {
            int b = cb0 + 32 * r;
            float hv[2];
            #pragma unroll
            for (int c = 0; c < 2; ++c) {
                int j = cj2 + c;
                float gi = part[0][0][b][j] + part[1][0][b][j]
                         + part[2][0][b][j] + part[3][0][b][j] + bi[0][c];
                float gf = part[0][1][b][j] + part[1][1][b][j]
                         + part[2][1][b][j] + part[3][1][b][j] + bi[1][c];
                float gg = part[0][2][b][j] + part[1][2][b][j]
                         + part[2][2][b][j] + part[3][2][b][j] + bi[2][c];
                float go = part[0][3][b][j] + part[1][3][b][j]
                         + part[2][3][b][j] + part[3][3][b][j] + bi[3][c];
                if (have_xg) {
                    gi += xgv[0][r][c];
                    gf += xgv[1][r][c];
                    gg += xgv[2][r][c];
                    go += xgv[3][r][c];
                }

                float ig = sigmoidf_fast(gi);
                float fg = sigmoidf_fast(gf);
                float gt = tanhf_fast(gg);
                float og = sigmoidf_fast(go);

                float cv = fg * creg[r][c] + ig * gt;
                creg[r][c] = cv;
                float h = og * tanhf_fast(cv);
                if (training)
                    h = h * (c ? kmv[r][1] : kmv[r][0]) * scale;
                hv[c] = h;
            }
            int cidx = b * 1024 + col0 + cj2;
            u32 packed = (u32)f2bf(hv[0]) | ((u32)f2bf(hv[1]) << 16);
            __hip_atomic_store((u32*)(hout + cidx), packed,
                               __ATOMIC_RELAXED, __HIP_MEMORY_SCOPE_AGENT);
            if (t == SEQ - 1) {
                out[cidx]     = hv[0];
                out[cidx + 1] = hv[1];
            }
        }

        asm volatile("s_waitcnt vmcnt(0)" ::: "memory");
        __syncthreads();
        if (tid == 0) {
            __hip_atomic_store(flags + ((u32)cu << 5), (u32)(t + 1),
                               __ATOMIC_RELAXED, __HIP_MEMORY_SCOPE_AGENT);
        }
    }

    if (cu == 0 && tid == 0) {
        __hip_atomic_store(flags + 2048, 1u,
                           __ATOMIC_RELAXED, __HIP_MEMORY_SCOPE_AGENT);
    }
}

extern "C" void kernel_launch(void* const* d_in, const int* in_sizes, int n_in,
                              void* d_out, int out_size, void* d_ws, size_t ws_size,
                              hipStream_t stream) {
    const float* x   = (const float*)d_in[0];
    const float* km  = (const float*)d_in[1];
    const float* wih = (const float*)d_in[2];
    const float* whh = (const float*)d_in[3];
    const float* bih = (const float*)d_in[4];
    const float* bhh = (const float*)d_in[5];
    const int*   tr  = (const int*)d_in[6];
    float* out = (float*)d_out;

    char* ws = (char*)d_ws;
    u16*   wc    = (u16*)(ws + WC_OFF);
    u16*   hseq  = (u16*)(ws + HSEQ_OFF);
    float* bias  = (float*)(ws + BIAS_OFF);
    u32*   flags = (u32*)(ws + FLAGS_OFF);

    const int use_xg = (ws_size >= WS_NEED_XG) ? 1 : 0;
    const int use_xc = (!use_xg && ws_size >= WS_NEED_XC) ? 1 : 0;
    float* xgp = use_xg ? (float*)(ws + XTRA_OFF) : nullptr;
    u16*   xc  = use_xc ? (u16*)(ws + XTRA_OFF) : nullptr;

    lstm_prep<<<dim3(2048), dim3(256), 0, stream>>>(wih, whh, bih, bhh, x,
                                                    wc, hseq, bias, flags,
                                                    xc, use_xc);
    if (use_xg) {
        u32* pf   = (u32*)(ws + PROBE_BASE);
        u16* areg = (u16*)(ws + AREG_OFF);
        probe_init<<<dim3(256), dim3(256), 0, stream>>>(pf, (u32*)areg);
        lstm_probe<<<dim3(NGRID), dim3(256), 0, stream>>>(pf,         wc, areg, 0);
        lstm_probe<<<dim3(NGRID), dim3(256), 0, stream>>>(pf + 4096,  wc, areg, 3);
        lstm_probe<<<dim3(NGRID), dim3(256), 0, stream>>>(pf + 8192,  wc, areg, 4);
        lstm_probe<<<dim3(NGRID), dim3(256), 0, stream>>>(pf + 12288, wc, areg, 5);
        lstm_xg<<<dim3(8192), dim3(256), 0, stream>>>(x, wc, xgp);
    }
    lstm_rec<<<dim3(NGRID), dim3(256), 0, stream>>>(x, xc, wc, bias, km, hseq,
                                                    out, flags, tr, xgp);
}